// Round 8
// baseline (3417.200 us; speedup 1.0000x reference)
//
#include <hip/hip_runtime.h>
#include <stdint.h>

// 3-layer LSTM (H=64, B=256, S=4096, DIN=1) + linear head.
// One block/batch element; 768 thr = 3 groups of 256 (group = layer), skewed
// pipeline (tick T: l0@T, l1@T-1, l2@T-2, y@T-3). Col-split matvec: thread
// (u,qt) does all 4 gate rows of unit u over col quarter qt (2 ds_read_b128).
// dotseg = exactly 8 v_dot2_f32_f16 on packed fp16 pairs; quad ops via DPP.
// R8: R7's VGPR=48 showed weights living in AGPRs (unified file) with per-tick
// copy-out — caused by cvt-chain pressure in the prologue at the weights'
// birth. Fix: prep kernel pre-converts weights to fp16 in d_ws; main prologue
// is 16 clean dwordx4 loads -> weights born cold into arch VGPRs.

#define SQ 4096
#define HH 64
#define NB 256

typedef _Float16 h2  __attribute__((ext_vector_type(2)));
typedef uint32_t uv8 __attribute__((ext_vector_type(8)));

__device__ __forceinline__ h2 bch2(uint32_t u) { return __builtin_bit_cast(h2, u); }

template<int CTRL>
__device__ __forceinline__ float fdpp(float v) {
    return __builtin_bit_cast(float,
        __builtin_amdgcn_mov_dpp(__builtin_bit_cast(int, v), CTRL, 0xF, 0xF, true));
}
#define DPP_XOR1 0xB1
#define DPP_XOR2 0x4E
#define DPP_XOR3 0x1B
#define DPP_ROR4 0x124
#define DPP_ROR8 0x128

__device__ __forceinline__ void pin(uv8& r) {
#pragma unroll
    for (int j = 0; j < 8; ++j) {
        uint32_t t = r[j];
        asm volatile("" : "+v"(t));
        r[j] = t;
    }
}

__device__ __forceinline__ float dotseg(uv8 w, uint4 a, uint4 b, float acc) {
    acc = __builtin_amdgcn_fdot2(bch2(w[0]), bch2(a.x), acc, false);
    acc = __builtin_amdgcn_fdot2(bch2(w[1]), bch2(a.y), acc, false);
    acc = __builtin_amdgcn_fdot2(bch2(w[2]), bch2(a.z), acc, false);
    acc = __builtin_amdgcn_fdot2(bch2(w[3]), bch2(a.w), acc, false);
    acc = __builtin_amdgcn_fdot2(bch2(w[4]), bch2(b.x), acc, false);
    acc = __builtin_amdgcn_fdot2(bch2(w[5]), bch2(b.y), acc, false);
    acc = __builtin_amdgcn_fdot2(bch2(w[6]), bch2(b.z), acc, false);
    acc = __builtin_amdgcn_fdot2(bch2(w[7]), bch2(b.w), acc, false);
    return acc;
}

// ---- prep: fp32 weights -> packed fp16 in ws (regions of 16384 halfs) ----
// region 0: Whh0 | 1: Wih1 | 2: Whh1 | 3: Wih2 | 4: Whh2
__global__ void prep_weights(const float* __restrict__ Whh0,
                             const float* __restrict__ Wih1,
                             const float* __restrict__ Whh1,
                             const float* __restrict__ Wih2,
                             const float* __restrict__ Whh2,
                             uint16_t* __restrict__ wsh) {
    const int i = blockIdx.x * 256 + threadIdx.x;        // 0..81919
    const int region = i >> 14;
    const int off = i & 16383;
    const float* src = (region == 0) ? Whh0 : (region == 1) ? Wih1
                     : (region == 2) ? Whh1 : (region == 3) ? Wih2 : Whh2;
    _Float16 v = (_Float16)src[off];
    wsh[i] = __builtin_bit_cast(uint16_t, v);
}

__global__ __launch_bounds__(768, 2) void lstm3_fused(
    const float* __restrict__ x,
    const float* __restrict__ Wih0,
    const float* __restrict__ bih0, const float* __restrict__ bhh0,
    const float* __restrict__ bih1, const float* __restrict__ bhh1,
    const float* __restrict__ bih2, const float* __restrict__ bhh2,
    const float* __restrict__ Wlin, const float* __restrict__ blin,
    const uint16_t* __restrict__ wsh,
    float* __restrict__ out)
{
    const int b   = blockIdx.x;
    const int tid = threadIdx.x;
    const int grp = tid >> 8;          // layer 0,1,2
    const int k   = tid & 255;
    const int u   = k >> 2;            // hidden unit
    const int qt  = k & 3;             // col quarter AND final gate index
    const int row = qt * HH + u;       // this thread's final gate row

    __shared__ __align__(16) float xrow[SQ];
    __shared__ __align__(16) uint4 hbf[2][3][8];   // [buf][layer][8x uint4 = 64 fp16]
    __shared__ __align__(16) float ybuf[2][16];    // per-row head partials

    for (int i = tid; i < SQ; i += 768) xrow[i] = x[b * SQ + i];
    if (tid < 48) ((uint4*)hbf)[tid] = make_uint4(0, 0, 0, 0);
    if (tid < 32) ((float*)ybuf)[tid] = 0.f;

    // ---- weights: packed fp16 segments from ws, clean dwordx4 loads ----
    const int regA = (grp == 0) ? 0 : (grp == 1) ? 1 : 3;
    const int regB = (grp == 1) ? 2 : 4;               // unused by grp0
    auto seg = [&](int region, int g) -> uv8 {
        const uint4* p = (const uint4*)(wsh + region * 16384 + (g * HH + u) * HH + 16 * qt);
        uint4 a = p[0], c = p[1];
        uv8 r = { a.x, a.y, a.z, a.w, c.x, c.y, c.z, c.w };
        return r;
    };
    uv8 wA0 = seg(regA, 0), wA1 = seg(regA, 1), wA2 = seg(regA, 2), wA3 = seg(regA, 3);
    pin(wA0); pin(wA1); pin(wA2); pin(wA3);
    uv8 wB0 = {}, wB1 = {}, wB2 = {}, wB3 = {};
    if (grp != 0) {
        wB0 = seg(regB, 0); wB1 = seg(regB, 1); wB2 = seg(regB, 2); wB3 = seg(regB, 3);
        pin(wB0); pin(wB1); pin(wB2); pin(wB3);
    }

    float bias = 0.f, wih0 = 0.f, wlin_u = 0.f;
    if (grp == 0) { bias = bih0[row] + bhh0[row]; wih0 = Wih0[row]; }
    else if (grp == 1) bias = bih1[row] + bhh1[row];
    else { bias = bih2[row] + bhh2[row]; if (qt == 0) wlin_u = Wlin[u]; }
    const float blin_v = blin[0];

    const int la = (grp == 2) ? 1 : 0;     // A-matvec h source layer
    const int lb = grp;                    // B-matvec h source layer (own)
    const uint4* pA[2] = { &hbf[0][la][2 * qt], &hbf[1][la][2 * qt] };
    const uint4* pB[2] = { &hbf[0][lb][2 * qt], &hbf[1][lb][2 * qt] };
    _Float16* pW[2] = { (_Float16*)&hbf[0][grp][0] + u, (_Float16*)&hbf[1][grp][0] + u };

    const bool b0c = qt & 1, b1c = (qt >> 1) & 1;
    const float s1 = (qt == 2) ? 2.f : 1.f;   // tanh = 2*sigm(2x)-1 for gate g
    const float o1 = (qt == 2) ? 1.f : 0.f;
    float cc = 0.f;                        // cell state (leaders qt==0)

    __syncthreads();

    auto tick = [&](int T, int rd) {
        const int wr = rd ^ 1;
        float p0, p1, p2, p3;

        const uint4 a0 = pA[rd][0], a1 = pA[rd][1];
        p0 = dotseg(wA0, a0, a1, 0.f);
        p1 = dotseg(wA1, a0, a1, 0.f);
        p2 = dotseg(wA2, a0, a1, 0.f);
        p3 = dotseg(wA3, a0, a1, 0.f);
        if (grp != 0) {
            const uint4 c0 = pB[rd][0], c1 = pB[rd][1];
            p0 = dotseg(wB0, c0, c1, p0);
            p1 = dotseg(wB1, c0, c1, p1);
            p2 = dotseg(wB2, c0, c1, p2);
            p3 = dotseg(wB3, c0, c1, p3);
        }

        // quad transpose-reduce (DPP): lane qt ends with full sum of gate qt
        float k0 = (b0c ? p1 : p0) + fdpp<DPP_XOR1>(b0c ? p0 : p1);
        float k1 = (b0c ? p3 : p2) + fdpp<DPP_XOR1>(b0c ? p2 : p3);
        float g  = (b1c ? k1 : k0) + fdpp<DPP_XOR2>(b1c ? k0 : k1);
        g += bias;
        if (grp == 0) g += wih0 * xrow[(T < SQ) ? T : 0];

        // activation + quad combine (DPP)
        float t = 1.f / (1.f + __expf(-s1 * g));
        const float act = s1 * t - o1;     // sigm for i,f,o; tanh for g
        const float v1 = fdpp<DPP_XOR1>(act);
        const float v2 = fdpp<DPP_XOR2>(act);
        const float v3 = fdpp<DPP_XOR3>(act);

        const int step = T - grp;
        float yv = 0.f;
        if (qt == 0 && step >= 0 && step < SQ) {
            cc = v1 * cc + act * v2;       // sigm(f)*c + sigm(i)*tanh(g)
            float tc = fminf(fmaxf(cc, -15.f), 15.f);
            float e  = __expf(-2.f * tc);
            float h  = v3 * ((1.f - e) / (1.f + e));   // sigm(o)*tanh(c)
            *pW[wr] = (_Float16)h;
            if (grp == 2) yv = wlin_u * h;
            if (step == SQ - 1) {
                out[NB * SQ + grp * NB * HH + b * HH + u] = h;
                out[NB * SQ + 3 * NB * HH + grp * NB * HH + b * HH + u] = cc;
            }
        }
        if (grp == 2) {
            yv += fdpp<DPP_XOR1>(yv);
            yv += fdpp<DPP_XOR2>(yv);
            yv += fdpp<DPP_ROR4>(yv);
            yv += fdpp<DPP_ROR8>(yv);
            if ((k & 15) == 0) ybuf[rd][k >> 4] = yv;
        }
        if (grp == 0 && u == HH - 1) {
            const int sy = T - 3;
            if (sy >= 0 && sy < SQ) {
                const float4 v = ((const float4*)ybuf[rd ^ 1])[qt];
                float s = (v.x + v.y) + (v.z + v.w);
                s += fdpp<DPP_XOR1>(s);
                s += fdpp<DPP_XOR2>(s);
                if (qt == 3) out[b * SQ + sy] = s + blin_v;
            }
        }
        __syncthreads();
    };

    for (int T = 0; T < SQ + 4; T += 2) {  // ticks 0..4099 (needs 0..4098)
        tick(T, 0);
        tick(T + 1, 1);
    }
}

extern "C" void kernel_launch(void* const* d_in, const int* in_sizes, int n_in,
                              void* d_out, int out_size, void* d_ws, size_t ws_size,
                              hipStream_t stream) {
    const float* x    = (const float*)d_in[0];
    const float* Wih0 = (const float*)d_in[1];
    const float* Whh0 = (const float*)d_in[2];
    const float* bih0 = (const float*)d_in[3];
    const float* bhh0 = (const float*)d_in[4];
    const float* Wih1 = (const float*)d_in[5];
    const float* Whh1 = (const float*)d_in[6];
    const float* bih1 = (const float*)d_in[7];
    const float* bhh1 = (const float*)d_in[8];
    const float* Wih2 = (const float*)d_in[9];
    const float* Whh2 = (const float*)d_in[10];
    const float* bih2 = (const float*)d_in[11];
    const float* bhh2 = (const float*)d_in[12];
    const float* Wlin = (const float*)d_in[13];
    const float* blin = (const float*)d_in[14];
    float* out = (float*)d_out;
    uint16_t* wsh = (uint16_t*)d_ws;

    prep_weights<<<320, 256, 0, stream>>>(Whh0, Wih1, Whh1, Wih2, Whh2, wsh);
    lstm3_fused<<<NB, 768, 0, stream>>>(x, Wih0, bih0, bhh0,
                                        bih1, bhh1, bih2, bhh2,
                                        Wlin, blin, wsh, out);
}